// Round 1
// baseline (82.075 us; speedup 1.0000x reference)
//
#include <hip/hip_runtime.h>

// Problem constants (fixed by setup_inputs): N=65536 tokens, K=8, E=64 experts.
#define TOTAL 524288   // N*K flattened assignments
#define NEXP  64
#define TOPK  8
#define GSIZE 256      // blocks
#define BLOCK 256      // threads per block
#define CHUNK (TOTAL / GSIZE)      // 2048 elements per block
#define ROUNDS (CHUNK / BLOCK)     // 8 rounds, 1 element/thread/round

// ---------------- Kernel A: per-block expert histogram ----------------
__global__ __launch_bounds__(BLOCK) void hist_kernel(const int* __restrict__ idx,
                                                     int* __restrict__ counts) {
    __shared__ int h[NEXP];
    const int tid = threadIdx.x;
    if (tid < NEXP) h[tid] = 0;
    __syncthreads();
    const int base = blockIdx.x * CHUNK;
#pragma unroll
    for (int r = 0; r < ROUNDS; r++) {
        int e = idx[base + r * BLOCK + tid];
        atomicAdd(&h[e], 1);
    }
    __syncthreads();
    if (tid < NEXP) counts[blockIdx.x * NEXP + tid] = h[tid];
}

// ---------------- Kernel B: offsets + stable scatter ----------------
__global__ __launch_bounds__(BLOCK) void scatter_kernel(const float* __restrict__ scores,
                                                        const int* __restrict__ idx,
                                                        const int* __restrict__ counts,
                                                        float* __restrict__ out_scores,
                                                        float* __restrict__ out_tok,
                                                        float* __restrict__ out_cnt) {
    __shared__ int blockOff[NEXP];   // start offset for this block, per expert
    __shared__ int totals[NEXP];     // expert totals -> then global exclusive scan
    __shared__ int running[NEXP];    // per-expert count consumed in earlier rounds
    __shared__ int cnt[4 * NEXP];    // per-wave per-expert count within a round

    const int tid = threadIdx.x;
    const int b   = blockIdx.x;

    // 64 threads: expert e = tid. Sum counts over all blocks; prefix over blocks < b.
    if (tid < NEXP) {
        int pre = 0, tot = 0;
        for (int bb = 0; bb < GSIZE; bb++) {
            int c = counts[bb * NEXP + tid];   // lanes 0..63 load contiguous ints
            pre += (bb < b) ? c : 0;
            tot += c;
        }
        totals[tid]   = tot;
        blockOff[tid] = pre;
        running[tid]  = 0;
        if (b == 0) out_cnt[tid] = (float)tot;   // num_tokens_per_expert (float32)
    }
    __syncthreads();
    // Exclusive scan over 64 experts (serial; trivial cost).
    if (tid == 0) {
        int acc = 0;
        for (int e = 0; e < NEXP; e++) { int t = totals[e]; totals[e] = acc; acc += t; }
    }
    __syncthreads();
    if (tid < NEXP) blockOff[tid] += totals[tid];
    // (loop-top barrier below covers this write before first use)

    const int lane = tid & 63;
    const int wave = tid >> 6;
    const unsigned long long ltmask = (1ULL << lane) - 1ULL;  // lanes below me
    const int base = b * CHUNK;

#pragma unroll
    for (int r = 0; r < ROUNDS; r++) {
        __syncthreads();            // prev round's running update / init complete
        cnt[tid] = 0;               // 4 waves x 64 experts
        __syncthreads();

        const int   i = base + r * BLOCK + tid;
        const int   e = idx[i];
        const float s = scores[i];

        // Mask of lanes in my wave with the same expert id (6 bits suffice, E=64).
        unsigned long long m = ~0ULL;
#pragma unroll
        for (int bit = 0; bit < 6; bit++) {
            unsigned long long bb = __ballot((e >> bit) & 1);
            m &= ((e >> bit) & 1) ? bb : ~bb;
        }
        const int inwave = __popcll(m & ltmask);
        const int leader = __ffsll((long long)m) - 1;
        if (lane == leader) cnt[wave * NEXP + e] = __popcll(m);
        __syncthreads();

        int rank = inwave + running[e];
        for (int w = 0; w < wave; w++) rank += cnt[w * NEXP + e];
        const int pos = blockOff[e] + rank;
        out_scores[pos] = s;
        out_tok[pos]    = (float)(i / TOPK);   // token index, exact in fp32 (< 2^24)
        __syncthreads();

        if (tid < NEXP)
            running[tid] += cnt[0 * NEXP + tid] + cnt[1 * NEXP + tid] +
                            cnt[2 * NEXP + tid] + cnt[3 * NEXP + tid];
    }
}

extern "C" void kernel_launch(void* const* d_in, const int* in_sizes, int n_in,
                              void* d_out, int out_size, void* d_ws, size_t ws_size,
                              hipStream_t stream) {
    const float* top_scores = (const float*)d_in[0];
    const int*   sel_idx    = (const int*)d_in[1];
    float*       out        = (float*)d_out;
    int*         counts     = (int*)d_ws;     // GSIZE*NEXP ints = 64 KB

    // d_out layout: [scores_sorted (TOTAL)] [token_idx_sorted (TOTAL)] [counts (NEXP)]
    float* out_scores = out;
    float* out_tok    = out + TOTAL;
    float* out_cnt    = out + 2 * TOTAL;

    hist_kernel<<<GSIZE, BLOCK, 0, stream>>>(sel_idx, counts);
    scatter_kernel<<<GSIZE, BLOCK, 0, stream>>>(top_scores, sel_idx, counts,
                                                out_scores, out_tok, out_cnt);
}